// Round 1
// baseline (237.868 us; speedup 1.0000x reference)
//
#include <hip/hip_runtime.h>
#include <hip/hip_bf16.h>
#include <stdint.h>

typedef float  f32x4  __attribute__((ext_vector_type(4)));
typedef __bf16 bf16x8 __attribute__((ext_vector_type(8)));
typedef unsigned short us4 __attribute__((ext_vector_type(4)));

#define NDIM 4096
#define DDIM 512

__device__ __forceinline__ unsigned short f2bf(float f) {
    union { float f; uint32_t u; } v; v.f = f;
    uint32_t u = v.u;
    u += 0x7FFFu + ((u >> 16) & 1u);   // round-to-nearest-even
    return (unsigned short)(u >> 16);
}

__global__ void dscale_kernel(const float* __restrict__ A, float* __restrict__ ds) {
    int i = blockIdx.x * blockDim.x + threadIdx.x;
    if (i < NDIM) ds[i] = rsqrtf(A[(size_t)i * (NDIM + 1)] + 1.0f);
}

// A (fp32, NxN) -> bf16 with +I on the diagonal
__global__ void cvtA_kernel(const float* __restrict__ A, unsigned short* __restrict__ out) {
    int i = blockIdx.x * blockDim.x + threadIdx.x;   // float4 index
    int e = i << 2;
    int row = e >> 12;          // /4096
    int col = e & 4095;
    f32x4 v = ((const f32x4*)A)[i];
    int d = row - col;
    if (d >= 0 && d < 4) v[d] += 1.0f;
    us4 o;
    o.x = f2bf(v.x); o.y = f2bf(v.y); o.z = f2bf(v.z); o.w = f2bf(v.w);
    ((us4*)out)[i] = o;
}

__global__ void cvt_kernel(const float* __restrict__ in, unsigned short* __restrict__ out, int n4) {
    int i = blockIdx.x * blockDim.x + threadIdx.x;
    if (i >= n4) return;
    f32x4 v = ((const f32x4*)in)[i];
    us4 o;
    o.x = f2bf(v.x); o.y = f2bf(v.y); o.z = f2bf(v.z); o.w = f2bf(v.w);
    ((us4*)out)[i] = o;
}

// C = A @ B^T.  A: [M x K] bf16 row-major (M = gridDim.y*128).
//               B: [Nr x K] bf16 row-major (Nr = gridDim.x*64).
// MODE 0: store bf16 TRANSPOSED  (C_t[n][m], ldc = M)
// MODE 1: store bf16 TRANSPOSED, scaled by ds[row m]
// MODE 2: store fp32 row-major, relu(ds[m] * acc)   (ldc = Nout)
// Tiles: BM=128, BN=64, BK=64; 4 waves (2x2), each wave 64x32 = 4x2 MFMA tiles.
template <int MODE>
__global__ __launch_bounds__(256, 2) void gemm_bt(
    const unsigned short* __restrict__ A,
    const unsigned short* __restrict__ B,
    void* __restrict__ C,
    const float* __restrict__ ds,
    int K, int ldc)
{
    __shared__ unsigned short lsA[128 * 64];  // 16 KB, rows of 64 bf16 (128B), XOR-16B swizzled
    __shared__ unsigned short lsB[64 * 64];   //  8 KB

    const int tid  = threadIdx.x;
    const int wid  = tid >> 6;
    const int lane = tid & 63;
    const int m0 = blockIdx.y * 128;
    const int n0 = blockIdx.x * 64;
    const int wm = (wid & 1) * 64;
    const int wn = (wid >> 1) * 32;

    // staging: lane l of instruction t covers LDS row t*8 + (l>>3), phys col (l&7)*16.
    // phys col holds logical col ((l&7)^(l>>3))*16  (XOR swizzle applied on the global side)
    const int lrow = lane >> 3;
    const int lcsw = ((lane & 7) ^ lrow) * 16;

    f32x4 acc[4][2];
    #pragma unroll
    for (int i = 0; i < 4; i++)
        #pragma unroll
        for (int j = 0; j < 2; j++) acc[i][j] = (f32x4)0.0f;

    // A: instr t = wid*4+i -> global rows m0 + wid*32 + i*8 + lrow
    const char* gA = (const char*)A + ((size_t)(m0 + wid * 32 + lrow) * K) * 2 + lcsw;
    // B: instr t = wid*2+i -> global rows n0 + wid*16 + i*8 + lrow
    const char* gB = (const char*)B + ((size_t)(n0 + wid * 16 + lrow) * K) * 2 + lcsw;
    const size_t rowstep = (size_t)8 * K * 2;

    for (int k0 = 0; k0 < K; k0 += 64) {
        const size_t kb = (size_t)k0 * 2;
        #pragma unroll
        for (int i = 0; i < 4; i++) {
            __builtin_amdgcn_global_load_lds(
                (const __attribute__((address_space(1))) void*)(gA + kb + (size_t)i * rowstep),
                (__attribute__((address_space(3))) void*)(&lsA[(wid * 4 + i) * 512]),
                16, 0, 0);
        }
        #pragma unroll
        for (int i = 0; i < 2; i++) {
            __builtin_amdgcn_global_load_lds(
                (const __attribute__((address_space(1))) void*)(gB + kb + (size_t)i * rowstep),
                (__attribute__((address_space(3))) void*)(&lsB[(wid * 2 + i) * 512]),
                16, 0, 0);
        }
        __syncthreads();

        #pragma unroll
        for (int ks = 0; ks < 2; ks++) {
            const int kboff = ks * 64 + (lane >> 4) * 16;  // byte offset in 128B row
            bf16x8 bfrag[2];
            #pragma unroll
            for (int nt = 0; nt < 2; nt++) {
                int r = wn + nt * 16 + (lane & 15);
                bfrag[nt] = *(const bf16x8*)((const char*)lsB + r * 128 + (kboff ^ ((r & 7) * 16)));
            }
            bf16x8 afrag[4];
            #pragma unroll
            for (int mt = 0; mt < 4; mt++) {
                int r = wm + mt * 16 + (lane & 15);
                afrag[mt] = *(const bf16x8*)((const char*)lsA + r * 128 + (kboff ^ ((r & 7) * 16)));
            }
            #pragma unroll
            for (int mt = 0; mt < 4; mt++)
                #pragma unroll
                for (int nt = 0; nt < 2; nt++)
                    acc[mt][nt] = __builtin_amdgcn_mfma_f32_16x16x32_bf16(
                        afrag[mt], bfrag[nt], acc[mt][nt], 0, 0, 0);
        }
        __syncthreads();
    }

    // epilogue.  C/D layout: col = lane&15, row = (lane>>4)*4 + reg  (m89/m91)
    const int col  = lane & 15;
    const int quad = lane >> 4;
    #pragma unroll
    for (int mt = 0; mt < 4; mt++) {
        const int gm0 = m0 + wm + mt * 16 + quad * 4;   // 4 consecutive rows
        f32x4 d;
        if (MODE >= 1) d = *(const f32x4*)(ds + gm0);
        else           d = (f32x4)1.0f;
        #pragma unroll
        for (int nt = 0; nt < 2; nt++) {
            const int gn = n0 + wn + nt * 16 + col;
            f32x4 v = acc[mt][nt];
            if (MODE <= 1) {
                us4 o;
                o.x = f2bf(v.x * d.x);
                o.y = f2bf(v.y * d.y);
                o.z = f2bf(v.z * d.z);
                o.w = f2bf(v.w * d.w);
                *(us4*)((unsigned short*)C + (size_t)gn * ldc + gm0) = o;
            } else {
                float* o = (float*)C + (size_t)gm0 * ldc + gn;
                o[0]             = fmaxf(v.x * d.x, 0.0f);
                o[ldc]           = fmaxf(v.y * d.y, 0.0f);
                o[2 * (size_t)ldc] = fmaxf(v.z * d.z, 0.0f);
                o[3 * (size_t)ldc] = fmaxf(v.w * d.w, 0.0f);
            }
        }
    }
}

extern "C" void kernel_launch(void* const* d_in, const int* in_sizes, int n_in,
                              void* d_out, int out_size, void* d_ws, size_t ws_size,
                              hipStream_t stream) {
    const float* X = (const float*)d_in[0];   // [4096 x 512]
    const float* A = (const float*)d_in[1];   // [4096 x 4096]
    const float* W = (const float*)d_in[2];   // [512 x 512]

    char* ws = (char*)d_ws;
    float*          dsc = (float*)ws;                                  // 16 KB
    unsigned short* A2  = (unsigned short*)(ws + (16u << 10));         // 32 MB  bf16 A+I
    unsigned short* Xb  = (unsigned short*)(ws + (16u << 10) + 33554432u);                 // 4 MB
    unsigned short* Wb  = (unsigned short*)(ws + (16u << 10) + 33554432u + 4194304u);      // 0.5 MB
    unsigned short* Yt  = (unsigned short*)(ws + (16u << 10) + 33554432u + 4194304u + 524288u);            // 4 MB  (X@W^T)^T [512][4096]
    unsigned short* T2  = (unsigned short*)(ws + (16u << 10) + 33554432u + 4194304u + 524288u + 4194304u); // 4 MB  (ds*temp)^T [512][4096]

    dscale_kernel<<<16, 256, 0, stream>>>(A, dsc);
    cvtA_kernel<<<16384, 256, 0, stream>>>(A, A2);
    cvt_kernel<<<2048, 256, 0, stream>>>(X, Xb, 524288);
    cvt_kernel<<<256, 256, 0, stream>>>(W, Wb, 65536);

    dim3 grid(8, 32), blk(256);
    // Yt = (Xb @ Wb^T)^T            [512][4096] bf16
    gemm_bt<0><<<grid, blk, 0, stream>>>(Xb, Wb, Yt, nullptr, 512, 4096);
    // T2 = (ds_row * (A2 @ Yt^T))^T [512][4096] bf16
    gemm_bt<1><<<grid, blk, 0, stream>>>(A2, Yt, T2, dsc, 4096, 4096);
    // out = relu(ds_row * (A2 @ T2^T))  [4096][512] fp32
    gemm_bt<2><<<grid, blk, 0, stream>>>(A2, T2, d_out, dsc, 4096, 512);
}

// Round 2
// 195.308 us; speedup vs baseline: 1.2179x; 1.2179x over previous
//
#include <hip/hip_runtime.h>
#include <hip/hip_bf16.h>
#include <stdint.h>

typedef float  f32x4  __attribute__((ext_vector_type(4)));
typedef __bf16 bf16x8 __attribute__((ext_vector_type(8)));
typedef unsigned short us4 __attribute__((ext_vector_type(4)));

#define NDIM 4096
#define DDIM 512

__device__ __forceinline__ unsigned short f2bf(float f) {
    union { float f; uint32_t u; } v; v.f = f;
    uint32_t u = v.u;
    u += 0x7FFFu + ((u >> 16) & 1u);   // round-to-nearest-even
    return (unsigned short)(u >> 16);
}

// Fused prep: block-range dispatch over {cvtA(+I), cvtX, cvtW, dscale}.
//   blocks [0, 16384)            : A fp32 -> bf16 with +I   (4096x4096, float4/thread)
//   blocks [16384, 18432)        : X fp32 -> bf16           (4096x512)
//   blocks [18432, 18688)        : W fp32 -> bf16           (512x512)
//   blocks [18688, 18704)        : ds[i] = rsqrt(A[i,i]+1)
__global__ void prep_kernel(const float* __restrict__ A, const float* __restrict__ X,
                            const float* __restrict__ W,
                            unsigned short* __restrict__ A2, unsigned short* __restrict__ Xb,
                            unsigned short* __restrict__ Wb, float* __restrict__ ds) {
    const int b = blockIdx.x, tid = threadIdx.x;
    if (b < 16384) {
        int i = b * 256 + tid;          // float4 index into A
        int e = i << 2;
        int row = e >> 12, col = e & 4095;
        f32x4 v = ((const f32x4*)A)[i];
        int d = row - col;
        if (d >= 0 && d < 4) v[d] += 1.0f;
        us4 o; o.x = f2bf(v.x); o.y = f2bf(v.y); o.z = f2bf(v.z); o.w = f2bf(v.w);
        ((us4*)A2)[i] = o;
    } else if (b < 18432) {
        int i = (b - 16384) * 256 + tid;
        f32x4 v = ((const f32x4*)X)[i];
        us4 o; o.x = f2bf(v.x); o.y = f2bf(v.y); o.z = f2bf(v.z); o.w = f2bf(v.w);
        ((us4*)Xb)[i] = o;
    } else if (b < 18688) {
        int i = (b - 18432) * 256 + tid;
        f32x4 v = ((const f32x4*)W)[i];
        us4 o; o.x = f2bf(v.x); o.y = f2bf(v.y); o.z = f2bf(v.z); o.w = f2bf(v.w);
        ((us4*)Wb)[i] = o;
    } else {
        int i = (b - 18688) * 256 + tid;
        if (i < NDIM) ds[i] = rsqrtf(A[(size_t)i * (NDIM + 1)] + 1.0f);
    }
}

// C = A @ B^T.  A: [M x K] bf16 row-major, B: [Nr x K] bf16 row-major.
// blockIdx.x = m-tile (BM=64), blockIdx.y = n-tile (BN=64).
//   -> linear id = m + n*gridDim.x, XCD = id%8 = m%8: all n-blocks of an
//      A-stripe co-locate on one XCD; the 0.5 MB stripe lives in its L2.
// MODE 0: store bf16 TRANSPOSED  (C_t[n][m], ldc = M)
// MODE 1: store bf16 TRANSPOSED, scaled by ds[row m]
// MODE 2: store fp32 row-major, relu(ds[m] * acc)   (ldc = Nout)
// 4 waves (2x2), each wave 32x32 = 2x2 MFMA tiles of 16x16x32.
template <int MODE>
__global__ __launch_bounds__(256, 2) void gemm_bt(
    const unsigned short* __restrict__ A,
    const unsigned short* __restrict__ B,
    void* __restrict__ C,
    const float* __restrict__ ds,
    int K, int ldc)
{
    __shared__ unsigned short lsA[64 * 64];  // 8 KB, rows of 128 B, XOR-16B swizzled
    __shared__ unsigned short lsB[64 * 64];  // 8 KB

    const int tid  = threadIdx.x;
    const int wid  = tid >> 6;
    const int lane = tid & 63;
    const int m0 = blockIdx.x * 64;
    const int n0 = blockIdx.y * 64;
    const int wm = (wid & 1) * 32;
    const int wn = (wid >> 1) * 32;

    // staging: instr t covers LDS rows t*8+(l>>3), phys 16B-col (l&7);
    // phys col holds logical col ((l&7)^(l>>3)) — XOR applied on global side.
    const int lrow = lane >> 3;
    const int lcsw = ((lane & 7) ^ lrow) * 16;

    f32x4 acc[2][2];
    #pragma unroll
    for (int i = 0; i < 2; i++)
        #pragma unroll
        for (int j = 0; j < 2; j++) acc[i][j] = (f32x4)0.0f;

    // A: instr t = wid*2+i -> global rows m0 + wid*16 + i*8 + lrow
    const char* gA = (const char*)A + ((size_t)(m0 + wid * 16 + lrow) * K) * 2 + lcsw;
    const char* gB = (const char*)B + ((size_t)(n0 + wid * 16 + lrow) * K) * 2 + lcsw;
    const size_t rowstep = (size_t)8 * K * 2;

    for (int k0 = 0; k0 < K; k0 += 64) {
        const size_t kb = (size_t)k0 * 2;
        #pragma unroll
        for (int i = 0; i < 2; i++) {
            __builtin_amdgcn_global_load_lds(
                (const __attribute__((address_space(1))) void*)(gA + kb + (size_t)i * rowstep),
                (__attribute__((address_space(3))) void*)(&lsA[(wid * 2 + i) * 512]),
                16, 0, 0);
            __builtin_amdgcn_global_load_lds(
                (const __attribute__((address_space(1))) void*)(gB + kb + (size_t)i * rowstep),
                (__attribute__((address_space(3))) void*)(&lsB[(wid * 2 + i) * 512]),
                16, 0, 0);
        }
        __syncthreads();

        #pragma unroll
        for (int ks = 0; ks < 2; ks++) {
            const int kboff = ks * 64 + (lane >> 4) * 16;  // byte offset in 128B row
            bf16x8 bfrag[2], afrag[2];
            #pragma unroll
            for (int nt = 0; nt < 2; nt++) {
                int r = wn + nt * 16 + (lane & 15);
                bfrag[nt] = *(const bf16x8*)((const char*)lsB + r * 128 + (kboff ^ ((r & 7) * 16)));
            }
            #pragma unroll
            for (int mt = 0; mt < 2; mt++) {
                int r = wm + mt * 16 + (lane & 15);
                afrag[mt] = *(const bf16x8*)((const char*)lsA + r * 128 + (kboff ^ ((r & 7) * 16)));
            }
            #pragma unroll
            for (int mt = 0; mt < 2; mt++)
                #pragma unroll
                for (int nt = 0; nt < 2; nt++)
                    acc[mt][nt] = __builtin_amdgcn_mfma_f32_16x16x32_bf16(
                        afrag[mt], bfrag[nt], acc[mt][nt], 0, 0, 0);
        }
        __syncthreads();
    }

    // epilogue.  C/D layout: col = lane&15, row = (lane>>4)*4 + reg
    const int col  = lane & 15;
    const int quad = lane >> 4;
    #pragma unroll
    for (int mt = 0; mt < 2; mt++) {
        const int gm0 = m0 + wm + mt * 16 + quad * 4;   // 4 consecutive rows
        f32x4 d;
        if (MODE >= 1) d = *(const f32x4*)(ds + gm0);
        else           d = (f32x4)1.0f;
        #pragma unroll
        for (int nt = 0; nt < 2; nt++) {
            const int gn = n0 + wn + nt * 16 + col;
            f32x4 v = acc[mt][nt];
            if (MODE <= 1) {
                us4 o;
                o.x = f2bf(v.x * d.x);
                o.y = f2bf(v.y * d.y);
                o.z = f2bf(v.z * d.z);
                o.w = f2bf(v.w * d.w);
                *(us4*)((unsigned short*)C + (size_t)gn * ldc + gm0) = o;
            } else {
                float* o = (float*)C + (size_t)gm0 * ldc + gn;
                o[0]               = fmaxf(v.x * d.x, 0.0f);
                o[ldc]             = fmaxf(v.y * d.y, 0.0f);
                o[2 * (size_t)ldc] = fmaxf(v.z * d.z, 0.0f);
                o[3 * (size_t)ldc] = fmaxf(v.w * d.w, 0.0f);
            }
        }
    }
}

extern "C" void kernel_launch(void* const* d_in, const int* in_sizes, int n_in,
                              void* d_out, int out_size, void* d_ws, size_t ws_size,
                              hipStream_t stream) {
    const float* X = (const float*)d_in[0];   // [4096 x 512]
    const float* A = (const float*)d_in[1];   // [4096 x 4096]
    const float* W = (const float*)d_in[2];   // [512 x 512]

    char* ws = (char*)d_ws;
    float*          dsc = (float*)ws;                                  // 16 KB
    unsigned short* A2  = (unsigned short*)(ws + (16u << 10));         // 32 MB  bf16 A+I
    unsigned short* Xb  = (unsigned short*)(ws + (16u << 10) + 33554432u);                 // 4 MB
    unsigned short* Wb  = (unsigned short*)(ws + (16u << 10) + 33554432u + 4194304u);      // 0.5 MB
    unsigned short* Yt  = (unsigned short*)(ws + (16u << 10) + 33554432u + 4194304u + 524288u);            // 4 MB  (X@W^T)^T [512][4096]
    unsigned short* T2  = (unsigned short*)(ws + (16u << 10) + 33554432u + 4194304u + 524288u + 4194304u); // 4 MB  (ds*temp)^T [512][4096]

    prep_kernel<<<18704, 256, 0, stream>>>(A, X, W, A2, Xb, Wb, dsc);

    dim3 grid(64, 8), blk(256);
    // Yt = (Xb @ Wb^T)^T            [512][4096] bf16
    gemm_bt<0><<<grid, blk, 0, stream>>>(Xb, Wb, Yt, nullptr, 512, 4096);
    // T2 = (ds_row * (A2 @ Yt^T))^T [512][4096] bf16
    gemm_bt<1><<<grid, blk, 0, stream>>>(A2, Yt, T2, dsc, 4096, 4096);
    // out = relu(ds_row * (A2 @ T2^T))  [4096][512] fp32
    gemm_bt<2><<<grid, blk, 0, stream>>>(A2, T2, d_out, dsc, 4096, 512);
}